// Round 18
// baseline (730.975 us; speedup 1.0000x reference)
//
#include <hip/hip_runtime.h>
#include <hip/hip_bf16.h>
#include <stdint.h>

// ChainOfExperts MoE: shared 2-expert MLP + top-2-of-16 routed experts.
// T=16384, D=2048, DR=512, DS=1024. bf16 MFMA, f32 router.
// R2: y_re + combine. R4: coalesced fused router. R5: T2 swizzle.
// R6: counted vmcnt ring. R7: compacted tiles. R8: split-K router.
// R9/R10: XCD clustering. R12: line-padded atomics. R16: bf16 y_sh combine.
// R17: shared GEMMs K-split counted-window (BK=64, never-drain vmcnt(4)).
// R18: re_l1 -> same K-split counted-window: BK=64, NT=32, 2x48KB dbuf,
//      3 loads/thread/K-half {A,B0,B1}; top vmcnt(3), mid vmcnt(3|0);
//      2 barriers/tile (was 2 per BK=32 tile -> half the boundaries,
//      2x MFMA per tile). re_l2 unchanged (not the bottleneck).

#define DEV static __device__ __forceinline__

typedef __attribute__((ext_vector_type(8))) short bf16x8;
typedef __attribute__((ext_vector_type(4))) float f32x4;

constexpr int T_TOK = 16384;
constexpr int DIM   = 2048;
constexpr int NEXP  = 16;
constexpr int DR_K  = 512;
constexpr int DS_K  = 1024;
constexpr int MAXROWS = 34816;
constexpr int MAXTILES = 272;

DEV void gload16(const void* g, void* l) {
  __builtin_amdgcn_global_load_lds(
      (const __attribute__((address_space(1))) unsigned int*)g,
      (__attribute__((address_space(3))) unsigned int*)l, 16, 0, 0);
}

DEV float silu_f(float v) { return v / (1.f + __expf(-v)); }

// ---------------- fused cast + router (R12 form) ----------------
__global__ __launch_bounds__(256) void cast_router_kernel(
    const float* __restrict__ x, __hip_bfloat16* __restrict__ xb,
    const float* __restrict__ rw_all, const int* __restrict__ step_p,
    int* __restrict__ tk_idx, float* __restrict__ tk_w) {
  int tid = threadIdx.x;
  int t0 = blockIdx.x * 8;
  __shared__ float xs[8][1024];
  __shared__ float red[4][4][8][4];

  float acc[8][4];
#pragma unroll
  for (int tk = 0; tk < 8; ++tk)
#pragma unroll
    for (int j = 0; j < 4; ++j) acc[tk][j] = 0.f;

  const float* rwbase = rw_all + (size_t)step_p[0] * DIM * NEXP;

#pragma unroll
  for (int half = 0; half < 2; ++half) {
#pragma unroll
    for (int tk = 0; tk < 8; ++tk) {
      const float4* xp = (const float4*)(x + (size_t)(t0 + tk) * DIM + half * 1024);
      float4 v = xp[tid];
      *(float4*)&xs[tk][tid * 4] = v;
      union { ushort4 u; __hip_bfloat16 h[4]; } o;
      o.h[0] = __float2bfloat16(v.x); o.h[1] = __float2bfloat16(v.y);
      o.h[2] = __float2bfloat16(v.z); o.h[3] = __float2bfloat16(v.w);
      *(ushort4*)(xb + (size_t)(t0 + tk) * DIM + half * 1024 + tid * 4) = o.u;
    }
    __syncthreads();
    const float4* rw4 = (const float4*)(rwbase + (size_t)half * 1024 * NEXP);
#pragma unroll 4
    for (int i = 0; i < 16; ++i) {
      int c = i * 256 + tid;
      int d = c >> 2;
      float4 wv = rw4[c];
#pragma unroll
      for (int tk = 0; tk < 8; ++tk) {
        float v = xs[tk][d];
        acc[tk][0] += v * wv.x; acc[tk][1] += v * wv.y;
        acc[tk][2] += v * wv.z; acc[tk][3] += v * wv.w;
      }
    }
    __syncthreads();
  }

#pragma unroll
  for (int m = 4; m < 64; m <<= 1) {
#pragma unroll
    for (int tk = 0; tk < 8; ++tk) {
      acc[tk][0] += __shfl_xor(acc[tk][0], m);
      acc[tk][1] += __shfl_xor(acc[tk][1], m);
      acc[tk][2] += __shfl_xor(acc[tk][2], m);
      acc[tk][3] += __shfl_xor(acc[tk][3], m);
    }
  }
  int lane = tid & 63, wvi = tid >> 6;
  if (lane < 4) {
#pragma unroll
    for (int tk = 0; tk < 8; ++tk) {
      float4 r = {acc[tk][0], acc[tk][1], acc[tk][2], acc[tk][3]};
      *(float4*)&red[wvi][lane][tk][0] = r;
    }
  }
  __syncthreads();
  if (tid < 8) {
    int t = t0 + tid;
    float lg[16];
#pragma unroll
    for (int e = 0; e < 16; ++e) {
      int cg = e >> 2, j = e & 3;
      lg[e] = red[0][cg][tid][j] + red[1][cg][tid][j] +
              red[2][cg][tid][j] + red[3][cg][tid][j];
    }
    float mx = lg[0];
    for (int i = 1; i < 16; ++i) mx = fmaxf(mx, lg[i]);
    float pr[16], sum = 0.f;
    for (int i = 0; i < 16; ++i) { pr[i] = expf(lg[i] - mx); sum += pr[i]; }
    float inv = 1.f / sum;
    int b0 = -1, b1 = -1; float w0 = -1.f, w1 = -1.f;
    for (int i = 0; i < 16; ++i) {
      float v = pr[i] * inv;
      if (v > w0)      { w1 = w0; b1 = b0; w0 = v; b0 = i; }
      else if (v > w1) { w1 = v; b1 = i; }
    }
    tk_idx[2 * t] = b0; tk_idx[2 * t + 1] = b1;
    tk_w[2 * t] = w0;   tk_w[2 * t + 1] = w1;
  }
}

// ---------------- histogram (R12) ----------------
__global__ __launch_bounds__(256) void hist_kernel(const int* __restrict__ tk_idx,
                                                   int* __restrict__ cnt_pad) {
  __shared__ int lc[16];
  int tid = threadIdx.x;
  if (tid < 16) lc[tid] = 0;
  __syncthreads();
  int base = blockIdx.x * 2048;
#pragma unroll
  for (int i = 0; i < 8; ++i)
    atomicAdd(&lc[tk_idx[base + i * 256 + tid]], 1);
  __syncthreads();
  if (tid < 16) atomicAdd(&cnt_pad[tid * 16], lc[tid]);
}

// ---------------- transpose + cast (R3) ----------------
__global__ __launch_bounds__(256) void transpose_cast(const float* __restrict__ in,
                                                      __hip_bfloat16* __restrict__ out,
                                                      int R, int C) {
  __shared__ float t[64][68];
  size_t bo = (size_t)blockIdx.z * R * C;
  in += bo; out += bo;
  int c0 = blockIdx.x * 64, r0 = blockIdx.y * 64;
  int tid = threadIdx.x;
  int rr = tid >> 2, cc0 = (tid & 3) * 16;
  const float* ip = in + (size_t)(r0 + rr) * C + c0 + cc0;
#pragma unroll
  for (int j = 0; j < 4; ++j)
    *(float4*)&t[rr][cc0 + 4 * j] = *(const float4*)(ip + 4 * j);
  __syncthreads();
  int wr = tid >> 2, wc0 = (tid & 3) * 16;
  union { bf16x8 v; __hip_bfloat16 h[8]; } o0, o1;
#pragma unroll
  for (int k = 0; k < 8; ++k) o0.h[k] = __float2bfloat16(t[wc0 + k][wr]);
#pragma unroll
  for (int k = 0; k < 8; ++k) o1.h[k] = __float2bfloat16(t[wc0 + 8 + k][wr]);
  __hip_bfloat16* op = out + (size_t)(c0 + wr) * R + r0 + wc0;
  *(bf16x8*)op = o0.v;
  *(bf16x8*)(op + 8) = o1.v;
}

// ---------------- scan (R12) ----------------
__global__ void scan_kernel(const int* __restrict__ cnt_pad, int* __restrict__ seg,
                            int* __restrict__ padded, int* __restrict__ tile_e,
                            int* __restrict__ tile_m0, int* __restrict__ n_tiles) {
  if (threadIdx.x == 0) {
    int off = 0, nt = 0;
    for (int e = 0; e < NEXP; ++e) {
      seg[e] = off;
      int pc = (cnt_pad[e * 16] + 127) & ~127;
      padded[e] = pc;
      for (int m = 0; m < pc; m += 128) { tile_e[nt] = e; tile_m0[nt] = m; ++nt; }
      off += pc;
    }
    seg[NEXP] = off;
    n_tiles[0] = nt;
  }
}

// ---------------- scatter (R12) ----------------
__global__ __launch_bounds__(256) void scatter_kernel(
    const int* __restrict__ tk_idx, const float* __restrict__ tk_w,
    const int* __restrict__ seg, int* __restrict__ cnt2_pad,
    int* __restrict__ tok_list, float* __restrict__ w_list,
    int* __restrict__ pos_list) {
  __shared__ int lh[16], lbase[16];
  int tid = threadIdx.x;
  if (tid < 16) lh[tid] = 0;
  __syncthreads();
  int t = blockIdx.x * 256 + tid;
  int e0 = tk_idx[2 * t], e1 = tk_idx[2 * t + 1];
  int s0 = atomicAdd(&lh[e0], 1);
  int s1 = atomicAdd(&lh[e1], 1);
  __syncthreads();
  if (tid < 16) lbase[tid] = atomicAdd(&cnt2_pad[tid * 16], lh[tid]);
  __syncthreads();
  int p0 = seg[e0] + lbase[e0] + s0;
  int p1 = seg[e1] + lbase[e1] + s1;
  tok_list[p0] = t; w_list[p0] = tk_w[2 * t];     pos_list[2 * t] = p0;
  tok_list[p1] = t; w_list[p1] = tk_w[2 * t + 1]; pos_list[2 * t + 1] = p1;
}

// ---------------- pad (R12) ----------------
__global__ void pad_kernel(const int* __restrict__ cnt_pad, const int* __restrict__ padded,
                           const int* __restrict__ seg, int* __restrict__ tok_list,
                           float* __restrict__ w_list) {
  int e = blockIdx.x;
  int c = cnt_pad[e * 16], pc = padded[e], s = seg[e];
  for (int i = c + threadIdx.x; i < pc; i += blockDim.x) {
    tok_list[s + i] = 0;
    w_list[s + i] = 0.f;
  }
}

DEV void swz_tile(int bid, int NB, int& tile, int& nb) {
  tile = 8 * (bid / (8 * NB)) + (bid & 7);
  nb = (bid >> 3) % NB;
}

// ---------------- shared GEMM: 256x256, BK=64, K-split counted-window (R17) ----------------
template <int MODE>
DEV void gemm_shared(const __hip_bfloat16* __restrict__ Abase,
                     const __hip_bfloat16* __restrict__ Bt,
                     const float* __restrict__ bias,
                     __hip_bfloat16* __restrict__ outb) {
  constexpr int KD = DIM;
  constexpr int NT = KD / 64;  // 32

  int tid = threadIdx.x;
  int ln = tid & 63, w8 = tid >> 6;
  int wm = w8 >> 2, wn = w8 & 3;
  int tile, nb;
  swz_tile(blockIdx.x, 8, tile, nb);
  int m0 = tile * 256;
  int n0 = nb * 256;

  __shared__ __align__(16) char lds[2 * 65536];

  int srow = tid >> 2;
  int schunk = (tid & 3) ^ ((tid >> 3) & 3);
  int browBase;
  if constexpr (MODE == 0) {
    int s = n0 >> 10, nn = n0 & 1023;
    browBase = s * DS_K + nn;
  } else {
    browBase = n0;
  }
  const __hip_bfloat16* aS0 = Abase + (size_t)(m0 + srow) * KD + schunk * 8;
  const __hip_bfloat16* aS1 = Abase + (size_t)(m0 + 128 + srow) * KD + schunk * 8;
  const __hip_bfloat16* bS0 = Bt + (size_t)(browBase + srow) * KD + schunk * 8;
  const __hip_bfloat16* bS1 = Bt + (size_t)(browBase + 128 + srow) * KD + schunk * 8;
  int d0 = w8 * 1024;
  int d1 = 8192 + w8 * 1024;

  gload16(aS0, lds + d0);              gload16(aS1, lds + d1);
  gload16(bS0, lds + 32768 + d0);      gload16(bS1, lds + 32768 + d1);
  gload16(aS0 + 32, lds + 16384 + d0); gload16(aS1 + 32, lds + 16384 + d1);
  gload16(bS0 + 32, lds + 49152 + d0); gload16(bS1 + 32, lds + 49152 + d1);

  f32x4 acc[8][4];
#pragma unroll
  for (int i = 0; i < 8; ++i)
#pragma unroll
    for (int j = 0; j < 4; ++j) acc[i][j] = (f32x4){0.f, 0.f, 0.f, 0.f};

  int cswz = (((ln >> 4) ^ ((ln >> 1) & 3)) << 4);
  int aByte = wm * 8192 + (ln & 15) * 64 + cswz;
  int bByte = 32768 + wn * 4096 + (ln & 15) * 64 + cswz;

  bf16x8 af[4], bfr[4];

  for (int t = 0; t < NT; ++t) {
    const char* buf = lds + (t & 1) * 65536;
    char* nxt = lds + ((t + 1) & 1) * 65536;
    bool pf = (t + 1) < NT;
    int ko = (t + 1) * 64;

    asm volatile("s_waitcnt vmcnt(4)" ::: "memory");
    __builtin_amdgcn_s_barrier();

    if (pf) {
      gload16(aS0 + ko, nxt + d0);
      gload16(aS1 + ko, nxt + d1);
    }
#pragma unroll
    for (int i = 0; i < 4; ++i) af[i] = *(const bf16x8*)(buf + aByte + i * 1024);
#pragma unroll
    for (int n = 0; n < 4; ++n) bfr[n] = *(const bf16x8*)(buf + bByte + n * 1024);
    __builtin_amdgcn_s_setprio(1);
#pragma unroll
    for (int i = 0; i < 4; ++i)
#pragma unroll
      for (int n = 0; n < 4; ++n)
        acc[i][n] = __builtin_amdgcn_mfma_f32_16x16x32_bf16(af[i], bfr[n], acc[i][n], 0, 0, 0);
    __builtin_amdgcn_s_setprio(0);

    if (pf) {
      gload16(bS0 + ko, nxt + 32768 + d0);
      gload16(bS1 + ko, nxt + 32768 + d1);
    }
#pragma unroll
    for (int i = 0; i < 4; ++i) af[i] = *(const bf16x8*)(buf + aByte + (4 + i) * 1024);
    __builtin_amdgcn_s_setprio(1);
#pragma unroll
    for (int i = 0; i < 4; ++i)
#pragma unroll
      for (int n = 0; n < 4; ++n)
        acc[4 + i][n] = __builtin_amdgcn_mfma_f32_16x16x32_bf16(af[i], bfr[n], acc[4 + i][n], 0, 0, 0);
    __builtin_amdgcn_s_setprio(0);

    if (pf) asm volatile("s_waitcnt vmcnt(4)" ::: "memory");
    else    asm volatile("s_waitcnt vmcnt(0)" ::: "memory");
    __builtin_amdgcn_s_barrier();

    if (pf) {
      gload16(aS0 + ko + 32, nxt + 16384 + d0);
      gload16(aS1 + ko + 32, nxt + 16384 + d1);
    }
#pragma unroll
    for (int i = 0; i < 4; ++i) af[i] = *(const bf16x8*)(buf + 16384 + aByte + i * 1024);
#pragma unroll
    for (int n = 0; n < 4; ++n) bfr[n] = *(const bf16x8*)(buf + 16384 + bByte + n * 1024);
    __builtin_amdgcn_s_setprio(1);
#pragma unroll
    for (int i = 0; i < 4; ++i)
#pragma unroll
      for (int n = 0; n < 4; ++n)
        acc[i][n] = __builtin_amdgcn_mfma_f32_16x16x32_bf16(af[i], bfr[n], acc[i][n], 0, 0, 0);
    __builtin_amdgcn_s_setprio(0);

    if (pf) {
      gload16(bS0 + ko + 32, nxt + 49152 + d0);
      gload16(bS1 + ko + 32, nxt + 49152 + d1);
    }
#pragma unroll
    for (int i = 0; i < 4; ++i) af[i] = *(const bf16x8*)(buf + 16384 + aByte + (4 + i) * 1024);
    __builtin_amdgcn_s_setprio(1);
#pragma unroll
    for (int i = 0; i < 4; ++i)
#pragma unroll
      for (int n = 0; n < 4; ++n)
        acc[4 + i][n] = __builtin_amdgcn_mfma_f32_16x16x32_bf16(af[i], bfr[n], acc[4 + i][n], 0, 0, 0);
    __builtin_amdgcn_s_setprio(0);
  }

  int colc = ln & 15;
  int rowb = (ln >> 4) << 2;
#pragma unroll
  for (int mi = 0; mi < 8; ++mi) {
    int mlb = wm * 128 + mi * 16 + rowb;
#pragma unroll
    for (int ni = 0; ni < 4; ++ni) {
      int ng = n0 + wn * 64 + ni * 16 + colc;
#pragma unroll
      for (int j = 0; j < 4; ++j) {
        float v = acc[mi][ni][j];
        if constexpr (MODE == 0) {
          float s = silu_f(v + bias[ng]);
          outb[(size_t)(m0 + mlb + j) * 2048 + ng] = __float2bfloat16(s);
        } else {
          outb[(size_t)(m0 + mlb + j) * DIM + ng] =
              __float2bfloat16(v + bias[ng] + bias[DIM + ng]);
        }
      }
    }
  }
}

// ---------------- re_l1: 128x256, BK=64, K-split counted-window (R18) ----------------
// Buffers 2x48KB: A-k0 @0 (8KB), A-k1 @8192, B-k0 @16384 (16KB), B-k1 @32768.
// 3 loads/thread/half in order {A, B0, B1}; prefetch distance 1 tile.
// Tile t: [vmcnt(3); bar] ph0{stage (t+1)-k0; read k0; 16 MFMA}
//         [vmcnt(pf?3:0); bar] ph1{stage (t+1)-k1; read k1; 16 MFMA}.
// WAR: (t+1)-staging issues after top-of-t barrier which follows all t-1
// reads of buf[(t+1)&1].
__global__ __launch_bounds__(512) void gemm_re_l1(
    const __hip_bfloat16* __restrict__ Abase,
    const __hip_bfloat16* __restrict__ Bt,
    const float* __restrict__ bias,
    __hip_bfloat16* __restrict__ outb,
    const int* __restrict__ tok_list, const float* __restrict__ w_list,
    const int* __restrict__ seg_off, const int* __restrict__ tile_e,
    const int* __restrict__ tile_m0, const int* __restrict__ n_tiles) {
  constexpr int KD = DIM;
  constexpr int NT = KD / 64;  // 32
  constexpr int BUFSZ = 49152;

  int tid = threadIdx.x;
  int ln = tid & 63, w8 = tid >> 6;
  int wm = w8 >> 2, wn = w8 & 3;

  __shared__ __align__(16) char lds[2 * BUFSZ];
  __shared__ int tk_s[128];
  __shared__ float w_s[128];

  int W = n_tiles[0] * 2;
  int q = (W + 7) >> 3;
  int xcd = blockIdx.x & 7, k = blockIdx.x >> 3;
  if (k >= q) return;
  int w = xcd * q + k;
  if (w >= W) return;
  int tl = w >> 1, nb = w & 1;

  int e = tile_e[tl];
  int m0 = tile_m0[tl];
  int n0 = nb * 256;
  int seg = seg_off[e];
  if (tid < 128) {
    tk_s[tid] = tok_list[seg + m0 + tid];
    w_s[tid] = w_list[seg + m0 + tid];
  }
  __syncthreads();

  int srow = tid >> 2;                        // 0..127
  int schunk = (tid & 3) ^ ((tid >> 3) & 3);  // pre-swizzled chunk
  const __hip_bfloat16* aS = Abase + (size_t)tk_s[srow] * KD + schunk * 8;
  const __hip_bfloat16* bS0 = Bt + (size_t)(e * DR_K + n0 + srow) * KD + schunk * 8;
  const __hip_bfloat16* bS1 = bS0 + (size_t)128 * KD;
  int dA = w8 * 1024;            // A slab dest (8KB)
  int dB0 = 16384 + w8 * 1024;   // B rows 0-127
  int dB1 = 16384 + 8192 + w8 * 1024;  // B rows 128-255

  // prologue: tile 0, halves k0 then k1, order {A,B0,B1} each
  gload16(aS, lds + dA);
  gload16(bS0, lds + dB0);
  gload16(bS1, lds + dB1);
  gload16(aS + 32, lds + 8192 + dA);
  gload16(bS0 + 32, lds + 16384 + dB0);
  gload16(bS1 + 32, lds + 16384 + dB1);

  f32x4 acc[4][4];
#pragma unroll
  for (int i = 0; i < 4; ++i)
#pragma unroll
    for (int j = 0; j < 4; ++j) acc[i][j] = (f32x4){0.f, 0.f, 0.f, 0.f};

  int cswz = (((ln >> 4) ^ ((ln >> 1) & 3)) << 4);
  int aByte = wm * 4096 + (ln & 15) * 64 + cswz;           // + mf*1024 (+8192 k1)
  int bByte = 16384 + wn * 4096 + (ln & 15) * 64 + cswz;   // + nf*1024 (+16384 k1)

  bf16x8 af[4], bfr[4];

  for (int t = 0; t < NT; ++t) {
    const char* buf = lds + (t & 1) * BUFSZ;
    char* nxt = lds + ((t + 1) & 1) * BUFSZ;
    bool pf = (t + 1) < NT;
    int ko = (t + 1) * 64;

    // top: this tile's k0 trio landed (k1 trio still flying)
    asm volatile("s_waitcnt vmcnt(3)" ::: "memory");
    __builtin_amdgcn_s_barrier();

    // ph0: stage (t+1)-k0; read k0; 16 MFMA
    if (pf) {
      gload16(aS + ko, nxt + dA);
      gload16(bS0 + ko, nxt + dB0);
      gload16(bS1 + ko, nxt + dB1);
    }
#pragma unroll
    for (int i = 0; i < 4; ++i) af[i] = *(const bf16x8*)(buf + aByte + i * 1024);
#pragma unroll
    for (int n = 0; n < 4; ++n) bfr[n] = *(const bf16x8*)(buf + bByte + n * 1024);
    __builtin_amdgcn_s_setprio(1);
#pragma unroll
    for (int i = 0; i < 4; ++i)
#pragma unroll
      for (int n = 0; n < 4; ++n)
        acc[i][n] = __builtin_amdgcn_mfma_f32_16x16x32_bf16(af[i], bfr[n], acc[i][n], 0, 0, 0);
    __builtin_amdgcn_s_setprio(0);

    // mid: this tile's k1 trio landed; (t+1)-k0 flying
    if (pf) asm volatile("s_waitcnt vmcnt(3)" ::: "memory");
    else    asm volatile("s_waitcnt vmcnt(0)" ::: "memory");
    __builtin_amdgcn_s_barrier();

    // ph1: stage (t+1)-k1; read k1; 16 MFMA
    if (pf) {
      gload16(aS + ko + 32, nxt + 8192 + dA);
      gload16(bS0 + ko + 32, nxt + 16384 + dB0);
      gload16(bS1 + ko + 32, nxt + 16384 + dB1);
    }
#pragma unroll
    for (int i = 0; i < 4; ++i) af[i] = *(const bf16x8*)(buf + 8192 + aByte + i * 1024);
#pragma unroll
    for (int n = 0; n < 4; ++n) bfr[n] = *(const bf16x8*)(buf + 16384 + bByte + n * 1024);
    __builtin_amdgcn_s_setprio(1);
#pragma unroll
    for (int i = 0; i < 4; ++i)
#pragma unroll
      for (int n = 0; n < 4; ++n)
        acc[i][n] = __builtin_amdgcn_mfma_f32_16x16x32_bf16(af[i], bfr[n], acc[i][n], 0, 0, 0);
    __builtin_amdgcn_s_setprio(0);
  }

  int colc = ln & 15;
  int rowb = (ln >> 4) << 2;
#pragma unroll
  for (int mi = 0; mi < 4; ++mi) {
    int mlb = wm * 64 + mi * 16 + rowb;
#pragma unroll
    for (int ni = 0; ni < 4; ++ni) {
      int ng = n0 + wn * 64 + ni * 16 + colc;
#pragma unroll
      for (int j = 0; j < 4; ++j) {
        int ml = mlb + j;
        float s = silu_f(acc[mi][ni][j] + bias[(size_t)e * DR_K + ng]) * w_s[ml];
        outb[((size_t)seg + m0 + ml) * DR_K + ng] = __float2bfloat16(s);
      }
    }
  }
}

// ---------------- re_l2: 128x256, BK=32, 3-slot ring, XCD-chunked (R10) ----------------
__global__ __launch_bounds__(512) void gemm_re_l2(
    const __hip_bfloat16* __restrict__ Abase,
    const __hip_bfloat16* __restrict__ Bt,
    const float* __restrict__ bias,
    __hip_bfloat16* __restrict__ outb,
    const int* __restrict__ tok_list, const float* __restrict__ w_list,
    const int* __restrict__ seg_off, const int* __restrict__ tile_e,
    const int* __restrict__ tile_m0, const int* __restrict__ n_tiles) {
  constexpr int KD = DR_K;
  constexpr int NT = KD / 32;
  constexpr int NB = 8;

  int tid = threadIdx.x;
  int ln = tid & 63, w8 = tid >> 6;
  int wm = w8 >> 2, wn = w8 & 3;

  __shared__ __align__(16) char lds[3 * 24576];
  __shared__ float w_s[128];

  int W = n_tiles[0] * NB;
  int q = (W + 7) >> 3;
  int xcd = blockIdx.x & 7, k = blockIdx.x >> 3;
  if (k >= q) return;
  int w = xcd * q + k;
  if (w >= W) return;
  int tl = w / NB, nb = w % NB;

  int e = tile_e[tl];
  int m0 = tile_m0[tl];
  int n0 = nb * 256;
  int seg = seg_off[e];
  if (tid < 128) w_s[tid] = w_list[seg + m0 + tid];
  __syncthreads();

  int srow = tid >> 2;
  int schunk = (tid & 3) ^ ((tid >> 3) & 3);
  const __hip_bfloat16* aS = Abase + (size_t)(seg + m0 + srow) * KD + schunk * 8;
  const __hip_bfloat16* bS0 = Bt + (size_t)(e * DIM + n0 + srow) * KD + schunk * 8;
  const __hip_bfloat16* bS1 = bS0 + (size_t)128 * KD;
  int wlds = w8 * 1024;

#pragma unroll
  for (int tt = 0; tt < 2; ++tt) {
    char* sl = lds + tt * 24576;
    int ko = tt * 32;
    gload16(aS + ko, sl + wlds);
    gload16(bS0 + ko, sl + 8192 + wlds);
    gload16(bS1 + ko, sl + 16384 + wlds);
  }
  asm volatile("s_waitcnt vmcnt(3)" ::: "memory");
  __builtin_amdgcn_s_barrier();

  f32x4 acc[4][4];
#pragma unroll
  for (int i = 0; i < 4; ++i)
#pragma unroll
    for (int j = 0; j < 4; ++j) acc[i][j] = (f32x4){0.f, 0.f, 0.f, 0.f};

  int rof = (ln & 15) * 64 + ((((ln >> 4) ^ (ln >> 1)) & 3) << 4);
  int aoffs = wm * 4096 + rof;
  int boffs = 8192 + wn * 4096 + rof;

  int s0 = 0;
  for (int t = 0; t < NT; ++t) {
    const char* sl = lds + s0 * 24576;
    int sd = s0 - 1; if (sd < 0) sd += 3;
    char* dst = lds + sd * 24576;
    bool pf = (t + 2) < NT;
    int ko = (t + 2) * 32;

    if (pf) {
      gload16(aS + ko, dst + wlds);
      gload16(bS0 + ko, dst + 8192 + wlds);
      gload16(bS1 + ko, dst + 16384 + wlds);
    }
    bf16x8 af[4], bfr[4];
#pragma unroll
    for (int fi = 0; fi < 4; ++fi)
      af[fi] = *(const bf16x8*)(sl + aoffs + fi * 1024);
#pragma unroll
    for (int ni = 0; ni < 4; ++ni)
      bfr[ni] = *(const bf16x8*)(sl + boffs + ni * 1024);
    __builtin_amdgcn_s_barrier();
    __builtin_amdgcn_s_setprio(1);
#pragma unroll
    for (int fi = 0; fi < 4; ++fi)
#pragma unroll
      for (int ni = 0; ni < 4; ++ni)
        acc[fi][ni] = __builtin_amdgcn_mfma_f32_16x16x32_bf16(af[fi], bfr[ni], acc[fi][ni], 0, 0, 0);
    __builtin_amdgcn_s_setprio(0);

    if (t + 1 < NT) {
      if (pf) asm volatile("s_waitcnt vmcnt(3)" ::: "memory");
      else    asm volatile("s_waitcnt vmcnt(0)" ::: "memory");
      __builtin_amdgcn_s_barrier();
    }
    s0 = (s0 + 1 == 3) ? 0 : s0 + 1;
  }

  int colc = ln & 15;
  int rowb = (ln >> 4) << 2;
#pragma unroll
  for (int mi = 0; mi < 4; ++mi) {
    int mlb = wm * 64 + mi * 16 + rowb;
#pragma unroll
    for (int ni = 0; ni < 4; ++ni) {
      int ng = n0 + wn * 64 + ni * 16 + colc;
#pragma unroll
      for (int j = 0; j < 4; ++j) {
        int ml = mlb + j;
        float wv = w_s[ml];
        outb[((size_t)seg + m0 + ml) * DIM + ng] =
            __float2bfloat16(acc[mi][ni][j] + wv * bias[(size_t)e * DIM + ng]);
      }
    }
  }
}

__global__ __launch_bounds__(512) void gemm_sh_l1(
    const __hip_bfloat16* A, const __hip_bfloat16* B, const float* bias,
    __hip_bfloat16* ob) {
  gemm_shared<0>(A, B, bias, ob);
}
__global__ __launch_bounds__(512) void gemm_sh_l2(
    const __hip_bfloat16* A, const __hip_bfloat16* B, const float* bias,
    __hip_bfloat16* ob) {
  gemm_shared<1>(A, B, bias, ob);
}

// ---------------- combine (sole out writer): out = y_sh + y_re[p0] + y_re[p1] ----------------
__global__ __launch_bounds__(256) void combine_kernel(float* __restrict__ out,
                                                      const __hip_bfloat16* __restrict__ y_sh,
                                                      const __hip_bfloat16* __restrict__ y_re,
                                                      const int* __restrict__ pos_list) {
  int t = blockIdx.x;
  int d0 = threadIdx.x << 3;
  int p0 = pos_list[2 * t], p1 = pos_list[2 * t + 1];
  union { bf16x8 v; __hip_bfloat16 h[8]; } s, a, b;
  s.v = *(const bf16x8*)(y_sh + (size_t)t * DIM + d0);
  a.v = *(const bf16x8*)(y_re + (size_t)p0 * DIM + d0);
  b.v = *(const bf16x8*)(y_re + (size_t)p1 * DIM + d0);
  float* o = out + (size_t)t * DIM + d0;
  float4 o0, o1;
  o0.x = __bfloat162float(s.h[0]) + __bfloat162float(a.h[0]) + __bfloat162float(b.h[0]);
  o0.y = __bfloat162float(s.h[1]) + __bfloat162float(a.h[1]) + __bfloat162float(b.h[1]);
  o0.z = __bfloat162float(s.h[2]) + __bfloat162float(a.h[2]) + __bfloat162float(b.h[2]);
  o0.w = __bfloat162float(s.h[3]) + __bfloat162float(a.h[3]) + __bfloat162float(b.h[3]);
  o1.x = __bfloat162float(s.h[4]) + __bfloat162float(a.h[4]) + __bfloat162float(b.h[4]);
  o1.y = __bfloat162float(s.h[5]) + __bfloat162float(a.h[5]) + __bfloat162float(b.h[5]);
  o1.z = __bfloat162float(s.h[6]) + __bfloat162float(a.h[6]) + __bfloat162float(b.h[6]);
  o1.w = __bfloat162float(s.h[7]) + __bfloat162float(a.h[7]) + __bfloat162float(b.h[7]);
  *(float4*)o = o0;
  *(float4*)(o + 4) = o1;
}

extern "C" void kernel_launch(void* const* d_in, const int* in_sizes, int n_in,
                              void* d_out, int out_size, void* d_ws, size_t ws_size,
                              hipStream_t stream) {
  const float* x     = (const float*)d_in[0];
  const int* step_p  = (const int*)d_in[1];
  const float* rw    = (const float*)d_in[2];
  const float* re_w1 = (const float*)d_in[3];
  const float* re_b1 = (const float*)d_in[4];
  const float* re_w2 = (const float*)d_in[5];
  const float* re_b2 = (const float*)d_in[6];
  const float* sh_w1 = (const float*)d_in[7];
  const float* sh_b1 = (const float*)d_in[8];
  const float* sh_w2 = (const float*)d_in[9];
  const float* sh_b2 = (const float*)d_in[10];
  float* out = (float*)d_out;

  char* w = (char*)d_ws;
  auto take = [&](size_t bytes) {
    char* p = w;
    w += (bytes + 255) & ~(size_t)255;
    return p;
  };
  __hip_bfloat16* xb     = (__hip_bfloat16*)take((size_t)T_TOK * DIM * 2);
  __hip_bfloat16* h_sh   = (__hip_bfloat16*)take((size_t)T_TOK * 2048 * 2);
  __hip_bfloat16* w1t_sh = (__hip_bfloat16*)take((size_t)2 * DS_K * DIM * 2);
  __hip_bfloat16* w2t_sh = (__hip_bfloat16*)take((size_t)DIM * 2048 * 2);
  __hip_bfloat16* h_re   = (__hip_bfloat16*)take((size_t)MAXROWS * DR_K * 2);
  __hip_bfloat16* w1t_re = (__hip_bfloat16*)take((size_t)NEXP * DR_K * DIM * 2);
  __hip_bfloat16* w2t_re = (__hip_bfloat16*)take((size_t)NEXP * DIM * DR_K * 2);
  __hip_bfloat16* y_sh   = (__hip_bfloat16*)take((size_t)T_TOK * DIM * 2);
  int* tk_idx   = (int*)take((size_t)T_TOK * 2 * 4);
  float* tk_w   = (float*)take((size_t)T_TOK * 2 * 4);
  int* ctrl     = (int*)take(4096);
  int* tok_list = (int*)take((size_t)MAXROWS * 4);
  float* w_list = (float*)take((size_t)MAXROWS * 4);
  int* pos_list = (int*)take((size_t)T_TOK * 2 * 4);
  int* tile_e   = (int*)take((size_t)MAXTILES * 4);
  int* tile_m0  = (int*)take((size_t)MAXTILES * 4);
  int* n_tiles  = (int*)take(256);
  int* cnt_pad  = ctrl;
  int* cnt2_pad = ctrl + 256;
  int* seg      = ctrl + 512;
  int* padded   = ctrl + 544;

  __hip_bfloat16* y_re = (__hip_bfloat16*)d_ws;  // aliases xb..w2t_sh (dead by then)

  hipMemsetAsync(ctrl, 0, 4096, stream);
  cast_router_kernel<<<T_TOK / 8, 256, 0, stream>>>(x, xb, rw, step_p, tk_idx, tk_w);
  transpose_cast<<<dim3(DS_K / 64, DIM / 64, 2), 256, 0, stream>>>(sh_w1, w1t_sh, DIM, DS_K);
  transpose_cast<<<dim3(DIM / 64, 2048 / 64, 1), 256, 0, stream>>>(sh_w2, w2t_sh, 2048, DIM);
  transpose_cast<<<dim3(DR_K / 64, DIM / 64, NEXP), 256, 0, stream>>>(re_w1, w1t_re, DIM, DR_K);
  transpose_cast<<<dim3(DIM / 64, DR_K / 64, NEXP), 256, 0, stream>>>(re_w2, w2t_re, DR_K, DIM);
  hist_kernel<<<16, 256, 0, stream>>>(tk_idx, cnt_pad);
  scan_kernel<<<1, 32, 0, stream>>>(cnt_pad, seg, padded, tile_e, tile_m0, n_tiles);
  scatter_kernel<<<T_TOK / 256, 256, 0, stream>>>(tk_idx, tk_w, seg, cnt2_pad,
                                                  tok_list, w_list, pos_list);
  pad_kernel<<<NEXP, 256, 0, stream>>>(cnt_pad, padded, seg, tok_list, w_list);

  gemm_sh_l1<<<64 * 8, 512, 0, stream>>>(xb, w1t_sh, sh_b1, h_sh);
  gemm_re_l1<<<MAXTILES * 2, 512, 0, stream>>>(xb, w1t_re, re_b1, h_re,
                                               tok_list, w_list, seg,
                                               tile_e, tile_m0, n_tiles);
  gemm_sh_l2<<<64 * 8, 512, 0, stream>>>(h_sh, w2t_sh, sh_b2, y_sh);
  gemm_re_l2<<<MAXTILES * 8, 512, 0, stream>>>(h_re, w2t_re, re_b2, y_re,
                                               tok_list, w_list, seg,
                                               tile_e, tile_m0, n_tiles);
  combine_kernel<<<T_TOK, 256, 0, stream>>>(out, y_sh, y_re, pos_list);
}

// Round 19
// 685.927 us; speedup vs baseline: 1.0657x; 1.0657x over previous
//
#include <hip/hip_runtime.h>
#include <hip/hip_bf16.h>
#include <stdint.h>

// ChainOfExperts MoE: shared 2-expert MLP + top-2-of-16 routed experts.
// T=16384, D=2048, DR=512, DS=1024. bf16 MFMA, f32 router.
// R2: y_re + combine. R4: coalesced fused router. R5: T2 swizzle.
// R6: counted vmcnt ring. R7: compacted tiles. R8: split-K router.
// R9/R10: XCD clustering. R12: line-padded atomics. R16: bf16 y_sh combine.
// R17: shared GEMMs K-split counted-window (BK=64, never-drain vmcnt(4)).
// R18 (REVERTED): re_l1 BK=64 dbuf needed 99KB LDS -> 1 block/CU -> slower.
// R19: restore R17 exactly (best measured: 686.7us).

#define DEV static __device__ __forceinline__

typedef __attribute__((ext_vector_type(8))) short bf16x8;
typedef __attribute__((ext_vector_type(4))) float f32x4;

constexpr int T_TOK = 16384;
constexpr int DIM   = 2048;
constexpr int NEXP  = 16;
constexpr int DR_K  = 512;
constexpr int DS_K  = 1024;
constexpr int MAXROWS = 34816;
constexpr int MAXTILES = 272;

DEV void gload16(const void* g, void* l) {
  __builtin_amdgcn_global_load_lds(
      (const __attribute__((address_space(1))) unsigned int*)g,
      (__attribute__((address_space(3))) unsigned int*)l, 16, 0, 0);
}

DEV float silu_f(float v) { return v / (1.f + __expf(-v)); }

// ---------------- fused cast + router (R12 form) ----------------
__global__ __launch_bounds__(256) void cast_router_kernel(
    const float* __restrict__ x, __hip_bfloat16* __restrict__ xb,
    const float* __restrict__ rw_all, const int* __restrict__ step_p,
    int* __restrict__ tk_idx, float* __restrict__ tk_w) {
  int tid = threadIdx.x;
  int t0 = blockIdx.x * 8;
  __shared__ float xs[8][1024];
  __shared__ float red[4][4][8][4];

  float acc[8][4];
#pragma unroll
  for (int tk = 0; tk < 8; ++tk)
#pragma unroll
    for (int j = 0; j < 4; ++j) acc[tk][j] = 0.f;

  const float* rwbase = rw_all + (size_t)step_p[0] * DIM * NEXP;

#pragma unroll
  for (int half = 0; half < 2; ++half) {
#pragma unroll
    for (int tk = 0; tk < 8; ++tk) {
      const float4* xp = (const float4*)(x + (size_t)(t0 + tk) * DIM + half * 1024);
      float4 v = xp[tid];
      *(float4*)&xs[tk][tid * 4] = v;
      union { ushort4 u; __hip_bfloat16 h[4]; } o;
      o.h[0] = __float2bfloat16(v.x); o.h[1] = __float2bfloat16(v.y);
      o.h[2] = __float2bfloat16(v.z); o.h[3] = __float2bfloat16(v.w);
      *(ushort4*)(xb + (size_t)(t0 + tk) * DIM + half * 1024 + tid * 4) = o.u;
    }
    __syncthreads();
    const float4* rw4 = (const float4*)(rwbase + (size_t)half * 1024 * NEXP);
#pragma unroll 4
    for (int i = 0; i < 16; ++i) {
      int c = i * 256 + tid;
      int d = c >> 2;
      float4 wv = rw4[c];
#pragma unroll
      for (int tk = 0; tk < 8; ++tk) {
        float v = xs[tk][d];
        acc[tk][0] += v * wv.x; acc[tk][1] += v * wv.y;
        acc[tk][2] += v * wv.z; acc[tk][3] += v * wv.w;
      }
    }
    __syncthreads();
  }

#pragma unroll
  for (int m = 4; m < 64; m <<= 1) {
#pragma unroll
    for (int tk = 0; tk < 8; ++tk) {
      acc[tk][0] += __shfl_xor(acc[tk][0], m);
      acc[tk][1] += __shfl_xor(acc[tk][1], m);
      acc[tk][2] += __shfl_xor(acc[tk][2], m);
      acc[tk][3] += __shfl_xor(acc[tk][3], m);
    }
  }
  int lane = tid & 63, wvi = tid >> 6;
  if (lane < 4) {
#pragma unroll
    for (int tk = 0; tk < 8; ++tk) {
      float4 r = {acc[tk][0], acc[tk][1], acc[tk][2], acc[tk][3]};
      *(float4*)&red[wvi][lane][tk][0] = r;
    }
  }
  __syncthreads();
  if (tid < 8) {
    int t = t0 + tid;
    float lg[16];
#pragma unroll
    for (int e = 0; e < 16; ++e) {
      int cg = e >> 2, j = e & 3;
      lg[e] = red[0][cg][tid][j] + red[1][cg][tid][j] +
              red[2][cg][tid][j] + red[3][cg][tid][j];
    }
    float mx = lg[0];
    for (int i = 1; i < 16; ++i) mx = fmaxf(mx, lg[i]);
    float pr[16], sum = 0.f;
    for (int i = 0; i < 16; ++i) { pr[i] = expf(lg[i] - mx); sum += pr[i]; }
    float inv = 1.f / sum;
    int b0 = -1, b1 = -1; float w0 = -1.f, w1 = -1.f;
    for (int i = 0; i < 16; ++i) {
      float v = pr[i] * inv;
      if (v > w0)      { w1 = w0; b1 = b0; w0 = v; b0 = i; }
      else if (v > w1) { w1 = v; b1 = i; }
    }
    tk_idx[2 * t] = b0; tk_idx[2 * t + 1] = b1;
    tk_w[2 * t] = w0;   tk_w[2 * t + 1] = w1;
  }
}

// ---------------- histogram (R12) ----------------
__global__ __launch_bounds__(256) void hist_kernel(const int* __restrict__ tk_idx,
                                                   int* __restrict__ cnt_pad) {
  __shared__ int lc[16];
  int tid = threadIdx.x;
  if (tid < 16) lc[tid] = 0;
  __syncthreads();
  int base = blockIdx.x * 2048;
#pragma unroll
  for (int i = 0; i < 8; ++i)
    atomicAdd(&lc[tk_idx[base + i * 256 + tid]], 1);
  __syncthreads();
  if (tid < 16) atomicAdd(&cnt_pad[tid * 16], lc[tid]);
}

// ---------------- transpose + cast (R3) ----------------
__global__ __launch_bounds__(256) void transpose_cast(const float* __restrict__ in,
                                                      __hip_bfloat16* __restrict__ out,
                                                      int R, int C) {
  __shared__ float t[64][68];
  size_t bo = (size_t)blockIdx.z * R * C;
  in += bo; out += bo;
  int c0 = blockIdx.x * 64, r0 = blockIdx.y * 64;
  int tid = threadIdx.x;
  int rr = tid >> 2, cc0 = (tid & 3) * 16;
  const float* ip = in + (size_t)(r0 + rr) * C + c0 + cc0;
#pragma unroll
  for (int j = 0; j < 4; ++j)
    *(float4*)&t[rr][cc0 + 4 * j] = *(const float4*)(ip + 4 * j);
  __syncthreads();
  int wr = tid >> 2, wc0 = (tid & 3) * 16;
  union { bf16x8 v; __hip_bfloat16 h[8]; } o0, o1;
#pragma unroll
  for (int k = 0; k < 8; ++k) o0.h[k] = __float2bfloat16(t[wc0 + k][wr]);
#pragma unroll
  for (int k = 0; k < 8; ++k) o1.h[k] = __float2bfloat16(t[wc0 + 8 + k][wr]);
  __hip_bfloat16* op = out + (size_t)(c0 + wr) * R + r0 + wc0;
  *(bf16x8*)op = o0.v;
  *(bf16x8*)(op + 8) = o1.v;
}

// ---------------- scan (R12) ----------------
__global__ void scan_kernel(const int* __restrict__ cnt_pad, int* __restrict__ seg,
                            int* __restrict__ padded, int* __restrict__ tile_e,
                            int* __restrict__ tile_m0, int* __restrict__ n_tiles) {
  if (threadIdx.x == 0) {
    int off = 0, nt = 0;
    for (int e = 0; e < NEXP; ++e) {
      seg[e] = off;
      int pc = (cnt_pad[e * 16] + 127) & ~127;
      padded[e] = pc;
      for (int m = 0; m < pc; m += 128) { tile_e[nt] = e; tile_m0[nt] = m; ++nt; }
      off += pc;
    }
    seg[NEXP] = off;
    n_tiles[0] = nt;
  }
}

// ---------------- scatter (R12) ----------------
__global__ __launch_bounds__(256) void scatter_kernel(
    const int* __restrict__ tk_idx, const float* __restrict__ tk_w,
    const int* __restrict__ seg, int* __restrict__ cnt2_pad,
    int* __restrict__ tok_list, float* __restrict__ w_list,
    int* __restrict__ pos_list) {
  __shared__ int lh[16], lbase[16];
  int tid = threadIdx.x;
  if (tid < 16) lh[tid] = 0;
  __syncthreads();
  int t = blockIdx.x * 256 + tid;
  int e0 = tk_idx[2 * t], e1 = tk_idx[2 * t + 1];
  int s0 = atomicAdd(&lh[e0], 1);
  int s1 = atomicAdd(&lh[e1], 1);
  __syncthreads();
  if (tid < 16) lbase[tid] = atomicAdd(&cnt2_pad[tid * 16], lh[tid]);
  __syncthreads();
  int p0 = seg[e0] + lbase[e0] + s0;
  int p1 = seg[e1] + lbase[e1] + s1;
  tok_list[p0] = t; w_list[p0] = tk_w[2 * t];     pos_list[2 * t] = p0;
  tok_list[p1] = t; w_list[p1] = tk_w[2 * t + 1]; pos_list[2 * t + 1] = p1;
}

// ---------------- pad (R12) ----------------
__global__ void pad_kernel(const int* __restrict__ cnt_pad, const int* __restrict__ padded,
                           const int* __restrict__ seg, int* __restrict__ tok_list,
                           float* __restrict__ w_list) {
  int e = blockIdx.x;
  int c = cnt_pad[e * 16], pc = padded[e], s = seg[e];
  for (int i = c + threadIdx.x; i < pc; i += blockDim.x) {
    tok_list[s + i] = 0;
    w_list[s + i] = 0.f;
  }
}

DEV void swz_tile(int bid, int NB, int& tile, int& nb) {
  tile = 8 * (bid / (8 * NB)) + (bid & 7);
  nb = (bid >> 3) % NB;
}

// ---------------- shared GEMM: 256x256, BK=64, K-split counted-window (R17) ----------------
template <int MODE>
DEV void gemm_shared(const __hip_bfloat16* __restrict__ Abase,
                     const __hip_bfloat16* __restrict__ Bt,
                     const float* __restrict__ bias,
                     __hip_bfloat16* __restrict__ outb) {
  constexpr int KD = DIM;
  constexpr int NT = KD / 64;  // 32

  int tid = threadIdx.x;
  int ln = tid & 63, w8 = tid >> 6;
  int wm = w8 >> 2, wn = w8 & 3;
  int tile, nb;
  swz_tile(blockIdx.x, 8, tile, nb);
  int m0 = tile * 256;
  int n0 = nb * 256;

  __shared__ __align__(16) char lds[2 * 65536];

  int srow = tid >> 2;
  int schunk = (tid & 3) ^ ((tid >> 3) & 3);
  int browBase;
  if constexpr (MODE == 0) {
    int s = n0 >> 10, nn = n0 & 1023;
    browBase = s * DS_K + nn;
  } else {
    browBase = n0;
  }
  const __hip_bfloat16* aS0 = Abase + (size_t)(m0 + srow) * KD + schunk * 8;
  const __hip_bfloat16* aS1 = Abase + (size_t)(m0 + 128 + srow) * KD + schunk * 8;
  const __hip_bfloat16* bS0 = Bt + (size_t)(browBase + srow) * KD + schunk * 8;
  const __hip_bfloat16* bS1 = Bt + (size_t)(browBase + 128 + srow) * KD + schunk * 8;
  int d0 = w8 * 1024;
  int d1 = 8192 + w8 * 1024;

  gload16(aS0, lds + d0);              gload16(aS1, lds + d1);
  gload16(bS0, lds + 32768 + d0);      gload16(bS1, lds + 32768 + d1);
  gload16(aS0 + 32, lds + 16384 + d0); gload16(aS1 + 32, lds + 16384 + d1);
  gload16(bS0 + 32, lds + 49152 + d0); gload16(bS1 + 32, lds + 49152 + d1);

  f32x4 acc[8][4];
#pragma unroll
  for (int i = 0; i < 8; ++i)
#pragma unroll
    for (int j = 0; j < 4; ++j) acc[i][j] = (f32x4){0.f, 0.f, 0.f, 0.f};

  int cswz = (((ln >> 4) ^ ((ln >> 1) & 3)) << 4);
  int aByte = wm * 8192 + (ln & 15) * 64 + cswz;
  int bByte = 32768 + wn * 4096 + (ln & 15) * 64 + cswz;

  bf16x8 af[4], bfr[4];

  for (int t = 0; t < NT; ++t) {
    const char* buf = lds + (t & 1) * 65536;
    char* nxt = lds + ((t + 1) & 1) * 65536;
    bool pf = (t + 1) < NT;
    int ko = (t + 1) * 64;

    asm volatile("s_waitcnt vmcnt(4)" ::: "memory");
    __builtin_amdgcn_s_barrier();

    if (pf) {
      gload16(aS0 + ko, nxt + d0);
      gload16(aS1 + ko, nxt + d1);
    }
#pragma unroll
    for (int i = 0; i < 4; ++i) af[i] = *(const bf16x8*)(buf + aByte + i * 1024);
#pragma unroll
    for (int n = 0; n < 4; ++n) bfr[n] = *(const bf16x8*)(buf + bByte + n * 1024);
    __builtin_amdgcn_s_setprio(1);
#pragma unroll
    for (int i = 0; i < 4; ++i)
#pragma unroll
      for (int n = 0; n < 4; ++n)
        acc[i][n] = __builtin_amdgcn_mfma_f32_16x16x32_bf16(af[i], bfr[n], acc[i][n], 0, 0, 0);
    __builtin_amdgcn_s_setprio(0);

    if (pf) {
      gload16(bS0 + ko, nxt + 32768 + d0);
      gload16(bS1 + ko, nxt + 32768 + d1);
    }
#pragma unroll
    for (int i = 0; i < 4; ++i) af[i] = *(const bf16x8*)(buf + aByte + (4 + i) * 1024);
    __builtin_amdgcn_s_setprio(1);
#pragma unroll
    for (int i = 0; i < 4; ++i)
#pragma unroll
      for (int n = 0; n < 4; ++n)
        acc[4 + i][n] = __builtin_amdgcn_mfma_f32_16x16x32_bf16(af[i], bfr[n], acc[4 + i][n], 0, 0, 0);
    __builtin_amdgcn_s_setprio(0);

    if (pf) asm volatile("s_waitcnt vmcnt(4)" ::: "memory");
    else    asm volatile("s_waitcnt vmcnt(0)" ::: "memory");
    __builtin_amdgcn_s_barrier();

    if (pf) {
      gload16(aS0 + ko + 32, nxt + 16384 + d0);
      gload16(aS1 + ko + 32, nxt + 16384 + d1);
    }
#pragma unroll
    for (int i = 0; i < 4; ++i) af[i] = *(const bf16x8*)(buf + 16384 + aByte + i * 1024);
#pragma unroll
    for (int n = 0; n < 4; ++n) bfr[n] = *(const bf16x8*)(buf + 16384 + bByte + n * 1024);
    __builtin_amdgcn_s_setprio(1);
#pragma unroll
    for (int i = 0; i < 4; ++i)
#pragma unroll
      for (int n = 0; n < 4; ++n)
        acc[i][n] = __builtin_amdgcn_mfma_f32_16x16x32_bf16(af[i], bfr[n], acc[i][n], 0, 0, 0);
    __builtin_amdgcn_s_setprio(0);

    if (pf) {
      gload16(bS0 + ko + 32, nxt + 49152 + d0);
      gload16(bS1 + ko + 32, nxt + 49152 + d1);
    }
#pragma unroll
    for (int i = 0; i < 4; ++i) af[i] = *(const bf16x8*)(buf + 16384 + aByte + (4 + i) * 1024);
    __builtin_amdgcn_s_setprio(1);
#pragma unroll
    for (int i = 0; i < 4; ++i)
#pragma unroll
      for (int n = 0; n < 4; ++n)
        acc[4 + i][n] = __builtin_amdgcn_mfma_f32_16x16x32_bf16(af[i], bfr[n], acc[4 + i][n], 0, 0, 0);
    __builtin_amdgcn_s_setprio(0);
  }

  int colc = ln & 15;
  int rowb = (ln >> 4) << 2;
#pragma unroll
  for (int mi = 0; mi < 8; ++mi) {
    int mlb = wm * 128 + mi * 16 + rowb;
#pragma unroll
    for (int ni = 0; ni < 4; ++ni) {
      int ng = n0 + wn * 64 + ni * 16 + colc;
#pragma unroll
      for (int j = 0; j < 4; ++j) {
        float v = acc[mi][ni][j];
        if constexpr (MODE == 0) {
          float s = silu_f(v + bias[ng]);
          outb[(size_t)(m0 + mlb + j) * 2048 + ng] = __float2bfloat16(s);
        } else {
          outb[(size_t)(m0 + mlb + j) * DIM + ng] =
              __float2bfloat16(v + bias[ng] + bias[DIM + ng]);
        }
      }
    }
  }
}

// ---------------- routed GEMM: 128x256, BK=32, 3-slot ring, XCD-chunked (R10) ----------------
template <int MODE, int NB>
DEV void gemm_routed(const __hip_bfloat16* __restrict__ Abase,
                     const __hip_bfloat16* __restrict__ Bt,
                     const float* __restrict__ bias,
                     __hip_bfloat16* __restrict__ outb,
                     const int* __restrict__ tok_list,
                     const float* __restrict__ w_list,
                     const int* __restrict__ seg_off,
                     const int* __restrict__ tile_e,
                     const int* __restrict__ tile_m0,
                     const int* __restrict__ n_tiles) {
  constexpr int KD = (MODE == 3) ? DR_K : DIM;
  constexpr int NT = KD / 32;

  int tid = threadIdx.x;
  int ln = tid & 63, w8 = tid >> 6;
  int wm = w8 >> 2, wn = w8 & 3;

  __shared__ __align__(16) char lds[3 * 24576];
  __shared__ int tk_s[128];
  __shared__ float w_s[128];

  int W = n_tiles[0] * NB;
  int q = (W + 7) >> 3;
  int xcd = blockIdx.x & 7, k = blockIdx.x >> 3;
  if (k >= q) return;
  int w = xcd * q + k;
  if (w >= W) return;
  int tl = w / NB, nb = w % NB;

  int e = tile_e[tl];
  int m0 = tile_m0[tl];
  int n0 = nb * 256;
  int seg = seg_off[e];
  if (tid < 128) {
    if constexpr (MODE == 2) tk_s[tid] = tok_list[seg + m0 + tid];
    w_s[tid] = w_list[seg + m0 + tid];
  }
  __syncthreads();

  int srow = tid >> 2;
  int schunk = (tid & 3) ^ ((tid >> 3) & 3);
  const __hip_bfloat16 *aS, *bS0, *bS1;
  {
    int ar, br0;
    if constexpr (MODE == 2) { ar = tk_s[srow]; br0 = e * DR_K + n0 + srow; }
    else                     { ar = seg + m0 + srow; br0 = e * DIM + n0 + srow; }
    aS  = Abase + (size_t)ar * KD + schunk * 8;
    bS0 = Bt + (size_t)br0 * KD + schunk * 8;
    bS1 = bS0 + (size_t)128 * KD;
  }
  int wlds = w8 * 1024;

#pragma unroll
  for (int tt = 0; tt < 2; ++tt) {
    char* sl = lds + tt * 24576;
    int ko = tt * 32;
    gload16(aS + ko, sl + wlds);
    gload16(bS0 + ko, sl + 8192 + wlds);
    gload16(bS1 + ko, sl + 16384 + wlds);
  }
  asm volatile("s_waitcnt vmcnt(3)" ::: "memory");
  __builtin_amdgcn_s_barrier();

  f32x4 acc[4][4];
#pragma unroll
  for (int i = 0; i < 4; ++i)
#pragma unroll
    for (int j = 0; j < 4; ++j) acc[i][j] = (f32x4){0.f, 0.f, 0.f, 0.f};

  int rof = (ln & 15) * 64 + ((((ln >> 4) ^ (ln >> 1)) & 3) << 4);
  int aoffs = wm * 4096 + rof;
  int boffs = 8192 + wn * 4096 + rof;

  int s0 = 0;
  for (int t = 0; t < NT; ++t) {
    const char* sl = lds + s0 * 24576;
    int sd = s0 - 1; if (sd < 0) sd += 3;
    char* dst = lds + sd * 24576;
    bool pf = (t + 2) < NT;
    int ko = (t + 2) * 32;

    if (pf) {
      gload16(aS + ko, dst + wlds);
      gload16(bS0 + ko, dst + 8192 + wlds);
      gload16(bS1 + ko, dst + 16384 + wlds);
    }
    bf16x8 af[4], bfr[4];
#pragma unroll
    for (int fi = 0; fi < 4; ++fi)
      af[fi] = *(const bf16x8*)(sl + aoffs + fi * 1024);
#pragma unroll
    for (int ni = 0; ni < 4; ++ni)
      bfr[ni] = *(const bf16x8*)(sl + boffs + ni * 1024);
    __builtin_amdgcn_s_barrier();
    __builtin_amdgcn_s_setprio(1);
#pragma unroll
    for (int fi = 0; fi < 4; ++fi)
#pragma unroll
      for (int ni = 0; ni < 4; ++ni)
        acc[fi][ni] = __builtin_amdgcn_mfma_f32_16x16x32_bf16(af[fi], bfr[ni], acc[fi][ni], 0, 0, 0);
    __builtin_amdgcn_s_setprio(0);

    if (t + 1 < NT) {
      if (pf) asm volatile("s_waitcnt vmcnt(3)" ::: "memory");
      else    asm volatile("s_waitcnt vmcnt(0)" ::: "memory");
      __builtin_amdgcn_s_barrier();
    }
    s0 = (s0 + 1 == 3) ? 0 : s0 + 1;
  }

  int colc = ln & 15;
  int rowb = (ln >> 4) << 2;
#pragma unroll
  for (int mi = 0; mi < 4; ++mi) {
    int mlb = wm * 64 + mi * 16 + rowb;
#pragma unroll
    for (int ni = 0; ni < 4; ++ni) {
      int ng = n0 + wn * 64 + ni * 16 + colc;
#pragma unroll
      for (int j = 0; j < 4; ++j) {
        float v = acc[mi][ni][j];
        int ml = mlb + j;
        if constexpr (MODE == 2) {
          float s = silu_f(v + bias[(size_t)e * DR_K + ng]) * w_s[ml];
          outb[((size_t)seg + m0 + ml) * DR_K + ng] = __float2bfloat16(s);
        } else {
          float wv = w_s[ml];
          outb[((size_t)seg + m0 + ml) * DIM + ng] =
              __float2bfloat16(v + wv * bias[(size_t)e * DIM + ng]);
        }
      }
    }
  }
}

__global__ __launch_bounds__(512) void gemm_sh_l1(
    const __hip_bfloat16* A, const __hip_bfloat16* B, const float* bias,
    __hip_bfloat16* ob) {
  gemm_shared<0>(A, B, bias, ob);
}
__global__ __launch_bounds__(512) void gemm_sh_l2(
    const __hip_bfloat16* A, const __hip_bfloat16* B, const float* bias,
    __hip_bfloat16* ob) {
  gemm_shared<1>(A, B, bias, ob);
}
__global__ __launch_bounds__(512) void gemm_re_l1(
    const __hip_bfloat16* A, const __hip_bfloat16* B, const float* bias,
    __hip_bfloat16* ob, const int* tok, const float* wl, const int* seg,
    const int* tl_e, const int* tl_m0, const int* ntl) {
  gemm_routed<2, 2>(A, B, bias, ob, tok, wl, seg, tl_e, tl_m0, ntl);
}
__global__ __launch_bounds__(512) void gemm_re_l2(
    const __hip_bfloat16* A, const __hip_bfloat16* B, const float* bias,
    __hip_bfloat16* ob, const int* tok, const float* wl, const int* seg,
    const int* tl_e, const int* tl_m0, const int* ntl) {
  gemm_routed<3, 8>(A, B, bias, ob, tok, wl, seg, tl_e, tl_m0, ntl);
}

// ---------------- combine (sole out writer): out = y_sh + y_re[p0] + y_re[p1] ----------------
__global__ __launch_bounds__(256) void combine_kernel(float* __restrict__ out,
                                                      const __hip_bfloat16* __restrict__ y_sh,
                                                      const __hip_bfloat16* __restrict__ y_re,
                                                      const int* __restrict__ pos_list) {
  int t = blockIdx.x;
  int d0 = threadIdx.x << 3;
  int p0 = pos_list[2 * t], p1 = pos_list[2 * t + 1];
  union { bf16x8 v; __hip_bfloat16 h[8]; } s, a, b;
  s.v = *(const bf16x8*)(y_sh + (size_t)t * DIM + d0);
  a.v = *(const bf16x8*)(y_re + (size_t)p0 * DIM + d0);
  b.v = *(const bf16x8*)(y_re + (size_t)p1 * DIM + d0);
  float* o = out + (size_t)t * DIM + d0;
  float4 o0, o1;
  o0.x = __bfloat162float(s.h[0]) + __bfloat162float(a.h[0]) + __bfloat162float(b.h[0]);
  o0.y = __bfloat162float(s.h[1]) + __bfloat162float(a.h[1]) + __bfloat162float(b.h[1]);
  o0.z = __bfloat162float(s.h[2]) + __bfloat162float(a.h[2]) + __bfloat162float(b.h[2]);
  o0.w = __bfloat162float(s.h[3]) + __bfloat162float(a.h[3]) + __bfloat162float(b.h[3]);
  o1.x = __bfloat162float(s.h[4]) + __bfloat162float(a.h[4]) + __bfloat162float(b.h[4]);
  o1.y = __bfloat162float(s.h[5]) + __bfloat162float(a.h[5]) + __bfloat162float(b.h[5]);
  o1.z = __bfloat162float(s.h[6]) + __bfloat162float(a.h[6]) + __bfloat162float(b.h[6]);
  o1.w = __bfloat162float(s.h[7]) + __bfloat162float(a.h[7]) + __bfloat162float(b.h[7]);
  *(float4*)o = o0;
  *(float4*)(o + 4) = o1;
}

extern "C" void kernel_launch(void* const* d_in, const int* in_sizes, int n_in,
                              void* d_out, int out_size, void* d_ws, size_t ws_size,
                              hipStream_t stream) {
  const float* x     = (const float*)d_in[0];
  const int* step_p  = (const int*)d_in[1];
  const float* rw    = (const float*)d_in[2];
  const float* re_w1 = (const float*)d_in[3];
  const float* re_b1 = (const float*)d_in[4];
  const float* re_w2 = (const float*)d_in[5];
  const float* re_b2 = (const float*)d_in[6];
  const float* sh_w1 = (const float*)d_in[7];
  const float* sh_b1 = (const float*)d_in[8];
  const float* sh_w2 = (const float*)d_in[9];
  const float* sh_b2 = (const float*)d_in[10];
  float* out = (float*)d_out;

  char* w = (char*)d_ws;
  auto take = [&](size_t bytes) {
    char* p = w;
    w += (bytes + 255) & ~(size_t)255;
    return p;
  };
  __hip_bfloat16* xb     = (__hip_bfloat16*)take((size_t)T_TOK * DIM * 2);
  __hip_bfloat16* h_sh   = (__hip_bfloat16*)take((size_t)T_TOK * 2048 * 2);
  __hip_bfloat16* w1t_sh = (__hip_bfloat16*)take((size_t)2 * DS_K * DIM * 2);
  __hip_bfloat16* w2t_sh = (__hip_bfloat16*)take((size_t)DIM * 2048 * 2);
  __hip_bfloat16* h_re   = (__hip_bfloat16*)take((size_t)MAXROWS * DR_K * 2);
  __hip_bfloat16* w1t_re = (__hip_bfloat16*)take((size_t)NEXP * DR_K * DIM * 2);
  __hip_bfloat16* w2t_re = (__hip_bfloat16*)take((size_t)NEXP * DIM * DR_K * 2);
  __hip_bfloat16* y_sh   = (__hip_bfloat16*)take((size_t)T_TOK * DIM * 2);
  int* tk_idx   = (int*)take((size_t)T_TOK * 2 * 4);
  float* tk_w   = (float*)take((size_t)T_TOK * 2 * 4);
  int* ctrl     = (int*)take(4096);
  int* tok_list = (int*)take((size_t)MAXROWS * 4);
  float* w_list = (float*)take((size_t)MAXROWS * 4);
  int* pos_list = (int*)take((size_t)T_TOK * 2 * 4);
  int* tile_e   = (int*)take((size_t)MAXTILES * 4);
  int* tile_m0  = (int*)take((size_t)MAXTILES * 4);
  int* n_tiles  = (int*)take(256);
  int* cnt_pad  = ctrl;
  int* cnt2_pad = ctrl + 256;
  int* seg      = ctrl + 512;
  int* padded   = ctrl + 544;

  __hip_bfloat16* y_re = (__hip_bfloat16*)d_ws;  // aliases xb..w2t_sh (dead by then)

  hipMemsetAsync(ctrl, 0, 4096, stream);
  cast_router_kernel<<<T_TOK / 8, 256, 0, stream>>>(x, xb, rw, step_p, tk_idx, tk_w);
  transpose_cast<<<dim3(DS_K / 64, DIM / 64, 2), 256, 0, stream>>>(sh_w1, w1t_sh, DIM, DS_K);
  transpose_cast<<<dim3(DIM / 64, 2048 / 64, 1), 256, 0, stream>>>(sh_w2, w2t_sh, 2048, DIM);
  transpose_cast<<<dim3(DR_K / 64, DIM / 64, NEXP), 256, 0, stream>>>(re_w1, w1t_re, DIM, DR_K);
  transpose_cast<<<dim3(DIM / 64, DR_K / 64, NEXP), 256, 0, stream>>>(re_w2, w2t_re, DR_K, DIM);
  hist_kernel<<<16, 256, 0, stream>>>(tk_idx, cnt_pad);
  scan_kernel<<<1, 32, 0, stream>>>(cnt_pad, seg, padded, tile_e, tile_m0, n_tiles);
  scatter_kernel<<<T_TOK / 256, 256, 0, stream>>>(tk_idx, tk_w, seg, cnt2_pad,
                                                  tok_list, w_list, pos_list);
  pad_kernel<<<NEXP, 256, 0, stream>>>(cnt_pad, padded, seg, tok_list, w_list);

  gemm_sh_l1<<<64 * 8, 512, 0, stream>>>(xb, w1t_sh, sh_b1, h_sh);
  gemm_re_l1<<<MAXTILES * 2, 512, 0, stream>>>(xb, w1t_re, re_b1, h_re,
                                               tok_list, w_list, seg,
                                               tile_e, tile_m0, n_tiles);
  gemm_sh_l2<<<64 * 8, 512, 0, stream>>>(h_sh, w2t_sh, sh_b2, y_sh);
  gemm_re_l2<<<MAXTILES * 8, 512, 0, stream>>>(h_re, w2t_re, re_b2, y_re,
                                               tok_list, w_list, seg,
                                               tile_e, tile_m0, n_tiles);
  combine_kernel<<<T_TOK, 256, 0, stream>>>(out, y_sh, y_re, pos_list);
}